// Round 5
// baseline (147.024 us; speedup 1.0000x reference)
//
#include <hip/hip_runtime.h>
#include <math.h>

// Static graph dims
#define BATCH   16384
#define IN_DIM  512
#define NH      128
#define NO      256
#define L2E     1.4426950408889634f

__device__ __forceinline__ float fast_rcp(float x) { return __builtin_amdgcn_rcpf(x); }
__device__ __forceinline__ float fast_exp2(float x) {
#if __has_builtin(__builtin_amdgcn_exp2f)
    return __builtin_amdgcn_exp2f(x);
#else
    return exp2f(x);
#endif
}
__device__ __forceinline__ int rfl(int v) { return __builtin_amdgcn_readfirstlane(v); }
__device__ __forceinline__ int rdl(int v, int l) { return __builtin_amdgcn_readlane(v, l); }

__device__ __forceinline__ float fast_tanh(float z) {
    float ex = fast_exp2(2.f * L2E * z);
    return 1.f - 2.f * fast_rcp(1.f + ex);
}
__device__ __forceinline__ float act_k(int a) {
    return (a == 2) ? (2.f * L2E) : ((a == 4) ? -L2E : 0.f);
}

__device__ __forceinline__ unsigned int f2bf_rne(float f) {
    unsigned int u = __float_as_uint(f);
    return (u + 0x7FFFu + ((u >> 16) & 1u)) >> 16;
}
__device__ __forceinline__ float bf2f(unsigned short h) { return __uint_as_float(((unsigned int)h) << 16); }
__device__ __forceinline__ unsigned short f2bf16s(float f) { return (unsigned short)f2bf_rne(f); }

__device__ __forceinline__ int lower_bound_dev(const int* __restrict__ arr, int n, int v) {
    int lo = 0, hi = n;
    while (lo < hi) { int m = (lo + hi) >> 1; if (arr[m] < v) lo = m + 1; else hi = m; }
    return lo;
}

#define FXS     514
#define FHS     65
#define MLDS    99072
#define RSTRIDE 128     // uint2 slots per row record (1 KB)

// ---------------- prep: per-row records, 8-way (act x src) sorted, hdr packed ----------------
// record slot 0: .x = c1|c2<<8|c3<<16|c4<<24  .y = c5|c6<<8|c7<<16|n<<24  (cumulative bounds)
// slots 1..n: .x = LDS offset (X: col ; H: (col-512)*65)  .y = prescaled weight bits
__global__ __launch_bounds__(512)
void prep_rows(const int* __restrict__ rows_h, const int* __restrict__ cols_h,
               const int* __restrict__ acts_h, const float* __restrict__ wh,
               const int* __restrict__ rows_o, const int* __restrict__ cols_o,
               const int* __restrict__ acts_o, const float* __restrict__ wo,
               int Eh, int Eo, uint2* __restrict__ rrh, uint2* __restrict__ rro)
{
    const int lane = (int)(threadIdx.x & 63);
    const int wid  = (int)((blockIdx.x * 512 + threadIdx.x) >> 6);
    if (wid >= NH + NO) return;
    const bool isH = wid < NH;
    const int r = isH ? wid : wid - NH;
    const int*   rows = isH ? rows_h : rows_o;
    const int*   cols = isH ? cols_h : cols_o;
    const int*   acts = isH ? acts_h : acts_o;
    const float* ww   = isH ? wh : wo;
    const int    E    = isH ? Eh : Eo;
    uint2* rec = (isH ? rrh : rro) + (size_t)r * RSTRIDE;

    const int e0 = lower_bound_dev(rows, E, r);
    const int e1 = lower_bound_dev(rows, E, r + 1);
    int n = e1 - e0; if (n > 127) n = 127;          // memory-safety clamp (unreachable)
    const unsigned long long lt = (1ull << lane) - 1ull;

    int cnt[8] = {0,0,0,0,0,0,0,0};
    for (int g = 0; g < n; g += 64) {
        int seg = -1;
        if (g + lane < n) {
            int e = e0 + g + lane;
            int a = acts[e];
            int col = cols[e];
            seg = (a - 1) + ((!isH && col >= IN_DIM) ? 4 : 0);
        }
        #pragma unroll
        for (int s = 0; s < 8; ++s) cnt[s] += __popcll(__ballot(seg == s));
    }
    int cum[9]; cum[0] = 0;
    #pragma unroll
    for (int s = 0; s < 8; ++s) cum[s + 1] = cum[s] + cnt[s];
    if (lane == 0) {
        unsigned hx = (unsigned)cum[1] | ((unsigned)cum[2] << 8) | ((unsigned)cum[3] << 16) | ((unsigned)cum[4] << 24);
        unsigned hy = (unsigned)cum[5] | ((unsigned)cum[6] << 8) | ((unsigned)cum[7] << 16) | ((unsigned)n << 24);
        rec[0] = make_uint2(hx, hy);
    }
    int pos[8];
    #pragma unroll
    for (int s = 0; s < 8; ++s) pos[s] = cum[s];
    for (int g = 0; g < n; g += 64) {
        int seg = -1; unsigned offv = 0, wbits = 0;
        if (g + lane < n) {
            int e = e0 + g + lane;
            int a = acts[e];
            int col = cols[e];
            bool hs = (!isH && col >= IN_DIM);
            seg = (a - 1) + (hs ? 4 : 0);
            offv = hs ? (unsigned)((col - IN_DIM) * FHS) : (unsigned)col;
            float w = ww[e];
            float ws = (a == 2) ? (2.f * L2E) * w : ((a == 4) ? -L2E * w : w);
            wbits = __float_as_uint(ws);
        }
        #pragma unroll
        for (int s = 0; s < 8; ++s) {
            unsigned long long m = __ballot(seg == s);
            if (seg == s) {
                int slot = 1 + pos[s] + __popcll(m & lt);
                rec[slot] = make_uint2(offv, wbits);
            }
            pos[s] += __popcll(m);
        }
    }
}

// ---------------- fused main ----------------
// LDS: X bf16 [64][514] = 65792 B + Hf f32 [128][65] = 33280 B -> 99072 B.
// Per row: one coalesced uint2 record load (prefetched), boundaries via readlane,
// 8 branch-free compile-time segments. Group-of-4 DS loads for MLP.
template<int ACT>
__device__ __forceinline__ float edge_apply(float acc, float v, float w) {
    if (ACT == 1)      return fmaf(v, w, acc);
    else if (ACT == 2) { float ex = fast_exp2(v * w); return acc + (1.f - 2.f * fast_rcp(1.f + ex)); }
    else if (ACT == 3) return acc + fmaxf(v * w, 0.f);
    else               { float ex = fast_exp2(v * w); return acc + fast_rcp(1.f + ex); }
}

template<int ACT, bool HSRC>
__device__ __forceinline__ void seg_run(float& acc,
                                        const unsigned short* __restrict__ Xl,  // X + lane*FXS
                                        const float* __restrict__ Hl,           // Hf + lane
                                        uint2 hv, int lo, int hi)
{
    int j = lo;
    // group-of-4: issue 4 DS loads back-to-back, then consume (staggered lgkmcnt)
    #pragma unroll 2
    for (; j + 3 < hi; j += 4) {
        int o0 = rdl((int)hv.x, j + 1);
        int o1 = rdl((int)hv.x, j + 2);
        int o2 = rdl((int)hv.x, j + 3);
        int o3 = rdl((int)hv.x, j + 4);
        float v0 = HSRC ? Hl[o0] : bf2f(Xl[o0]);
        float v1 = HSRC ? Hl[o1] : bf2f(Xl[o1]);
        float v2 = HSRC ? Hl[o2] : bf2f(Xl[o2]);
        float v3 = HSRC ? Hl[o3] : bf2f(Xl[o3]);
        float w0 = __uint_as_float((unsigned)rdl((int)hv.y, j + 1));
        float w1 = __uint_as_float((unsigned)rdl((int)hv.y, j + 2));
        float w2 = __uint_as_float((unsigned)rdl((int)hv.y, j + 3));
        float w3 = __uint_as_float((unsigned)rdl((int)hv.y, j + 4));
        acc = edge_apply<ACT>(acc, v0, w0);
        acc = edge_apply<ACT>(acc, v1, w1);
        acc = edge_apply<ACT>(acc, v2, w2);
        acc = edge_apply<ACT>(acc, v3, w3);
    }
    for (; j < hi; ++j) {
        int o = rdl((int)hv.x, j + 1);
        float v = HSRC ? Hl[o] : bf2f(Xl[o]);
        float w = __uint_as_float((unsigned)rdl((int)hv.y, j + 1));
        acc = edge_apply<ACT>(acc, v, w);
    }
}

template<bool OUT>
__device__ __forceinline__ float row_body(uint2 hv, const uint2* __restrict__ grow,
                                          const unsigned short* __restrict__ Xl,
                                          const float* __restrict__ Hl)
{
    const int ux = rdl((int)hv.x, 0), uy = rdl((int)hv.y, 0);
    const int c1 = ux & 255, c2 = (ux >> 8) & 255, c3 = (ux >> 16) & 255, c4 = (int)((unsigned)ux >> 24);
    const int c5 = uy & 255, c6 = (uy >> 8) & 255, c7 = (uy >> 16) & 255, n  = (int)((unsigned)uy >> 24);
    float acc = 0.f;
    if (n <= 63) {
        seg_run<1,false>(acc, Xl, Hl, hv, 0,  c1);
        seg_run<2,false>(acc, Xl, Hl, hv, c1, c2);
        seg_run<3,false>(acc, Xl, Hl, hv, c2, c3);
        seg_run<4,false>(acc, Xl, Hl, hv, c3, c4);
        if (OUT) {
            seg_run<1,true>(acc, Xl, Hl, hv, c4, c5);
            seg_run<2,true>(acc, Xl, Hl, hv, c5, c6);
            seg_run<3,true>(acc, Xl, Hl, hv, c6, c7);
            seg_run<4,true>(acc, Xl, Hl, hv, c7, n);
        }
    } else {
        // unreachable in practice (P < 1e-12): uniform global walk of the record
        for (int j = 0; j < n; ++j) {
            int soff = rfl((int)grow[1 + j].x);
            float w  = __int_as_float(rfl((int)grow[1 + j].y));
            int seg = (j < c1) ? 0 : (j < c2) ? 1 : (j < c3) ? 2 : (j < c4) ? 3
                    : (j < c5) ? 4 : (j < c6) ? 5 : (j < c7) ? 6 : 7;
            float v = (seg >= 4) ? Hl[soff] : bf2f(Xl[soff]);
            int a = (seg & 3) + 1;
            if (a == 1) acc = fmaf(v, w, acc);
            else if (a == 2) { float ex = fast_exp2(v * w); acc += 1.f - 2.f * fast_rcp(1.f + ex); }
            else if (a == 3) acc += fmaxf(v * w, 0.f);
            else { float ex = fast_exp2(v * w); acc += fast_rcp(1.f + ex); }
        }
    }
    return acc;
}

__global__ __launch_bounds__(1024)
void fused_main(const float* __restrict__ x,
                const uint2* __restrict__ rrh, const uint2* __restrict__ rro,
                float* __restrict__ out)
{
    extern __shared__ char lds[];
    unsigned short* X   = (unsigned short*)lds;
    float*          Hf  = (float*)(lds + 65792);
    float*          OBT = (float*)lds;                  // overlays X/H after compute
    const int tid  = (int)threadIdx.x;
    const int lane = tid & 63;
    const int wv   = tid >> 6;
    const int rb   = (int)blockIdx.x * 64;
    const unsigned short* Xl = X + (size_t)lane * FXS;
    const float*          Hl = Hf + lane;

    // ---- stage x slab -> bf16 X[64][514], coalesced float4 reads ----
    {
        const float4* xv = (const float4*)(x + (size_t)rb * IN_DIM);
        #pragma unroll
        for (int kk = 0; kk < 8; ++kk) {
            int v = tid + kk * 1024;
            int rr = v >> 7, i = v & 127;
            float4 f = xv[v];
            unsigned int lo = f2bf_rne(f.x) | (f2bf_rne(f.y) << 16);
            unsigned int hi = f2bf_rne(f.z) | (f2bf_rne(f.w) << 16);
            unsigned int* dst = (unsigned int*)&X[rr * FXS + i * 4];
            dst[0] = lo; dst[1] = hi;
        }
    }
    __syncthreads();

    // ---- hidden: wave wv -> rows wv*8..+7, record prefetch pipeline ----
    {
        uint2 hv = rrh[(size_t)(wv * 8) * RSTRIDE + lane];
        for (int q = 0; q < 8; ++q) {
            const int r = wv * 8 + q;
            uint2 hvn = hv;
            if (q < 7) hvn = rrh[(size_t)(r + 1) * RSTRIDE + lane];
            float acc = row_body<false>(hv, rrh + (size_t)r * RSTRIDE, Xl, Hl);
            Hf[r * FHS + lane] = acc;
            hv = hvn;
        }
    }
    __syncthreads();

    // ---- output: wave wv -> rows wv*16..+15, results kept in regs ----
    float res[NO / 16];
    {
        uint2 hv = rro[(size_t)(wv * 16) * RSTRIDE + lane];
        #pragma unroll 1
        for (int q = 0; q < 16; ++q) {
            const int r = wv * 16 + q;
            uint2 hvn = hv;
            if (q < 15) hvn = rro[(size_t)(r + 1) * RSTRIDE + lane];
            res[q] = fast_tanh(row_body<true>(hv, rro + (size_t)r * RSTRIDE, Xl, Hl));
            hv = hvn;
        }
    }
    __syncthreads();

    // ---- OBT transpose (stride 65 -> bank = r + lane, conflict-free) ----
    #pragma unroll
    for (int q = 0; q < NO / 16; ++q)
        OBT[(wv * (NO / 16) + q) * FHS + lane] = res[q];
    __syncthreads();
    // lanes read scattered cols (c = lane + i*64 -> bank = lane + b), stores coalesced 256B/wave
    #pragma unroll
    for (int s = 0; s < 4; ++s) {
        const int b = wv * 4 + s;
        #pragma unroll
        for (int i = 0; i < 4; ++i) {
            const int c = lane + i * 64;
            out[(size_t)(rb + b) * NO + c] = OBT[c * FHS + b];
        }
    }
}

// =============== fallback: single fused kernel, no workspace ===============
#define FT      1024
#define FBPB    64
#define FHS2    65
#define FOBTS   260
#define FLDS    (99072 + 1544)
__device__ __forceinline__ float edge_act2(float z, int a, float k) {
    float ex = fast_exp2(k * z);
    float rc = fast_rcp(1.f + ex);
    return (a == 2) ? (1.f - 2.f * rc) : ((a == 4) ? rc : ((a == 3) ? fmaxf(z, 0.f) : z));
}
__global__ __launch_bounds__(FT)
void wann_fused(const float* __restrict__ x,
                const int* __restrict__ rows_h, const int* __restrict__ cols_h,
                const int* __restrict__ acts_h, const float* __restrict__ wh,
                const int* __restrict__ rows_o, const int* __restrict__ cols_o,
                const int* __restrict__ acts_o, const float* __restrict__ wo,
                float* __restrict__ out, int Eh, int Eo)
{
    extern __shared__ char lds[];
    unsigned short* X   = (unsigned short*)lds;
    float*          H   = (float*)(lds + 65792);
    float*          OBT = (float*)lds;
    int*            offsH = (int*)(lds + 99072);
    int*            offsO = offsH + (NH + 1);
    const int tid  = threadIdx.x;
    const int lane = tid & 63;
    const int wv   = tid >> 6;
    const int rb   = blockIdx.x * FBPB;
    const int* wh_i = (const int*)wh;
    const int* wo_i = (const int*)wo;
    {
        const float4* xv = (const float4*)(x + (size_t)rb * IN_DIM);
        #pragma unroll
        for (int kk = 0; kk < (FBPB * IN_DIM / 4) / FT; ++kk) {
            int v = tid + kk * FT;
            int r = v >> 7, i = v & 127;
            float4 f = xv[v];
            unsigned int lo = (unsigned int)f2bf16s(f.x) | ((unsigned int)f2bf16s(f.y) << 16);
            unsigned int hi = (unsigned int)f2bf16s(f.z) | ((unsigned int)f2bf16s(f.w) << 16);
            unsigned int* dst = (unsigned int*)&X[r * FXS + i * 4];
            dst[0] = lo; dst[1] = hi;
        }
    }
    if (tid <= NH) offsH[tid] = lower_bound_dev(rows_h, Eh, tid);
    else if (tid <= NH + 1 + NO) offsO[tid - (NH + 1)] = lower_bound_dev(rows_o, Eo, tid - (NH + 1));
    __syncthreads();
    for (int r = wv * (NH / 16); r < (wv + 1) * (NH / 16); ++r) {
        const int e0 = rfl(offsH[r]); const int e1 = rfl(offsH[r + 1]);
        float acc = 0.f;
        #pragma unroll 4
        for (int e = e0; e < e1; ++e) {
            int col = rfl(cols_h[e]); int a = rfl(acts_h[e]);
            float w = __int_as_float(rfl(wh_i[e]));
            acc += edge_act2(bf2f(X[lane * FXS + col]) * w, a, act_k(a));
        }
        H[r * FHS2 + lane] = acc;
    }
    __syncthreads();
    float res[NO / 16];
    #pragma unroll
    for (int rr = 0; rr < NO / 16; ++rr) {
        const int r = wv * (NO / 16) + rr;
        const int e0 = rfl(offsO[r]); const int e1 = rfl(offsO[r + 1]);
        float acc = 0.f;
        #pragma unroll 4
        for (int e = e0; e < e1; ++e) {
            int col = rfl(cols_o[e]); int a = rfl(acts_o[e]);
            float w = __int_as_float(rfl(wo_i[e]));
            float v = (col < IN_DIM) ? bf2f(X[lane * FXS + col]) : H[(col - IN_DIM) * FHS2 + lane];
            acc += edge_act2(v * w, a, act_k(a));
        }
        res[rr] = fast_tanh(acc);
    }
    __syncthreads();
    #pragma unroll
    for (int rr = 0; rr < NO / 16; ++rr)
        OBT[lane * FOBTS + wv * (NO / 16) + rr] = res[rr];
    __syncthreads();
    #pragma unroll
    for (int kk = 0; kk < (FBPB * NO / 4) / FT; ++kk) {
        int v = tid + kk * FT;
        int c4 = v & 63, b = v >> 6;
        float4 o = *(const float4*)&OBT[b * FOBTS + c4 * 4];
        *(float4*)&out[(size_t)(rb + b) * NO + c4 * 4] = o;
    }
}

extern "C" void kernel_launch(void* const* d_in, const int* in_sizes, int n_in,
                              void* d_out, int out_size, void* d_ws, size_t ws_size,
                              hipStream_t stream) {
    const float* x      = (const float*)d_in[0];
    const float* wh     = (const float*)d_in[1];
    const float* wo     = (const float*)d_in[2];
    const int*   rows_h = (const int*)d_in[3];
    const int*   cols_h = (const int*)d_in[4];
    const int*   acts_h = (const int*)d_in[5];
    const int*   rows_o = (const int*)d_in[6];
    const int*   cols_o = (const int*)d_in[7];
    const int*   acts_o = (const int*)d_in[8];
    float*       out    = (float*)d_out;

    const int Eh = in_sizes[1];
    const int Eo = in_sizes[2];

    // ws layout: [rrh: NH rows x 1KB][rro: NO rows x 1KB]
    char*  ws  = (char*)d_ws;
    uint2* rrh = (uint2*)ws;
    uint2* rro = (uint2*)(ws + (size_t)NH * RSTRIDE * 8);
    size_t need = (size_t)(NH + NO) * RSTRIDE * 8;

    if (ws_size >= need) {
        prep_rows<<<(NH + NO) * 64 / 512, 512, 0, stream>>>(
            rows_h, cols_h, acts_h, wh, rows_o, cols_o, acts_o, wo,
            Eh, Eo, rrh, rro);
        fused_main<<<BATCH / 64, 1024, MLDS, stream>>>(x, rrh, rro, out);
    } else {
        wann_fused<<<BATCH / FBPB, FT, FLDS, stream>>>(
            x, rows_h, cols_h, acts_h, wh, rows_o, cols_o, acts_o, wo, out, Eh, Eo);
    }
}

// Round 6
// 144.599 us; speedup vs baseline: 1.0168x; 1.0168x over previous
//
#include <hip/hip_runtime.h>
#include <math.h>

// Static graph dims
#define BATCH   16384
#define IN_DIM  512
#define NH      128
#define NO      256
#define L2E     1.4426950408889634f

__device__ __forceinline__ float fast_rcp(float x) { return __builtin_amdgcn_rcpf(x); }
__device__ __forceinline__ float fast_exp2(float x) {
#if __has_builtin(__builtin_amdgcn_exp2f)
    return __builtin_amdgcn_exp2f(x);
#else
    return exp2f(x);
#endif
}
__device__ __forceinline__ int rfl(int v) { return __builtin_amdgcn_readfirstlane(v); }
__device__ __forceinline__ int rdl(int v, int l) { return __builtin_amdgcn_readlane(v, l); }

__device__ __forceinline__ float fast_tanh(float z) {
    float ex = fast_exp2(2.f * L2E * z);
    return 1.f - 2.f * fast_rcp(1.f + ex);
}
__device__ __forceinline__ float act_k(int a) {
    return (a == 2) ? (2.f * L2E) : ((a == 4) ? -L2E : 0.f);
}

__device__ __forceinline__ unsigned int f2bf_rne(float f) {
    unsigned int u = __float_as_uint(f);
    return (u + 0x7FFFu + ((u >> 16) & 1u)) >> 16;
}
__device__ __forceinline__ float bf2f(unsigned short h) { return __uint_as_float(((unsigned int)h) << 16); }
__device__ __forceinline__ unsigned short f2bf16s(float f) { return (unsigned short)f2bf_rne(f); }

__device__ __forceinline__ int lower_bound_dev(const int* __restrict__ arr, int n, int v) {
    int lo = 0, hi = n;
    while (lo < hi) { int m = (lo + hi) >> 1; if (arr[m] < v) lo = m + 1; else hi = m; }
    return lo;
}

#define FXS     514
#define FHS     65
#define MLDS    99072
#define RSU     128     // u32 slots per row record (512 B): [hx, hy, edge0..125]
#define FASTN   62      // edges 0..61 live in lanes 2..63 of the first 64 slots

// ---------------- prep: per-row records, 8-way (act x src) sorted ----------------
// slot 0: c1|c2<<8|c3<<16|c4<<24   slot 1: c5|c6<<8|c7<<16|n<<24  (cumulative bounds)
// slot 2+j: edge j = [w22 | off10]; w22 = RN-rounded top bits of prescaled f32 weight,
// off10 = col (X-src) or col-512 (H-src). All decode is SALU in the consumer.
__global__ __launch_bounds__(512)
void prep_rows(const int* __restrict__ rows_h, const int* __restrict__ cols_h,
               const int* __restrict__ acts_h, const float* __restrict__ wh,
               const int* __restrict__ rows_o, const int* __restrict__ cols_o,
               const int* __restrict__ acts_o, const float* __restrict__ wo,
               int Eh, int Eo, unsigned* __restrict__ rrh, unsigned* __restrict__ rro)
{
    const int lane = (int)(threadIdx.x & 63);
    const int wid  = (int)((blockIdx.x * 512 + threadIdx.x) >> 6);
    if (wid >= NH + NO) return;
    const bool isH = wid < NH;
    const int r = isH ? wid : wid - NH;
    const int*   rows = isH ? rows_h : rows_o;
    const int*   cols = isH ? cols_h : cols_o;
    const int*   acts = isH ? acts_h : acts_o;
    const float* ww   = isH ? wh : wo;
    const int    E    = isH ? Eh : Eo;
    unsigned* rec = (isH ? rrh : rro) + (size_t)r * RSU;

    const int e0 = lower_bound_dev(rows, E, r);
    const int e1 = lower_bound_dev(rows, E, r + 1);
    int n = e1 - e0; if (n > 126) n = 126;          // memory-safety clamp (unreachable)
    const unsigned long long lt = (1ull << lane) - 1ull;

    int cnt[8] = {0,0,0,0,0,0,0,0};
    for (int g = 0; g < n; g += 64) {
        int seg = -1;
        if (g + lane < n) {
            int e = e0 + g + lane;
            int a = acts[e];
            int col = cols[e];
            seg = (a - 1) + ((!isH && col >= IN_DIM) ? 4 : 0);
        }
        #pragma unroll
        for (int s = 0; s < 8; ++s) cnt[s] += __popcll(__ballot(seg == s));
    }
    int cum[9]; cum[0] = 0;
    #pragma unroll
    for (int s = 0; s < 8; ++s) cum[s + 1] = cum[s] + cnt[s];
    if (lane == 0) {
        rec[0] = (unsigned)cum[1] | ((unsigned)cum[2] << 8) | ((unsigned)cum[3] << 16) | ((unsigned)cum[4] << 24);
        rec[1] = (unsigned)cum[5] | ((unsigned)cum[6] << 8) | ((unsigned)cum[7] << 16) | ((unsigned)n << 24);
    }
    int pos[8];
    #pragma unroll
    for (int s = 0; s < 8; ++s) pos[s] = cum[s];
    for (int g = 0; g < n; g += 64) {
        int seg = -1; unsigned payload = 0;
        if (g + lane < n) {
            int e = e0 + g + lane;
            int a = acts[e];
            int col = cols[e];
            bool hs = (!isH && col >= IN_DIM);
            seg = (a - 1) + (hs ? 4 : 0);
            unsigned offv = hs ? (unsigned)(col - IN_DIM) : (unsigned)col;   // < 1024
            float w = ww[e];
            float ws = (a == 2) ? (2.f * L2E) * w : ((a == 4) ? -L2E * w : w);
            unsigned wb = (__float_as_uint(ws) + 0x200u) & 0xFFFFFC00u;      // RN to 22 bits
            payload = wb | offv;
        }
        #pragma unroll
        for (int s = 0; s < 8; ++s) {
            unsigned long long m = __ballot(seg == s);
            if (seg == s) rec[2 + pos[s] + __popcll(m & lt)] = payload;
            pos[s] += __popcll(m);
        }
    }
}

// ---------------- fused main ----------------
// LDS: X bf16 [64][514] = 65792 B + Hf f32 [128][65] = 33280 B -> 99072 B.
// Per edge: 1 v_readlane; weight/offset decode entirely SALU (s_and / s_mul);
// identity edge = v_fmac with SGPR weight. Hoisted +1-per-tanh-edge.
template<int ACT>
__device__ __forceinline__ float app(float acc, float v, float w) {
    if (ACT == 1)      return fmaf(v, w, acc);
    else if (ACT == 2) { float ex = fast_exp2(v * w); return fmaf(-2.f, fast_rcp(1.f + ex), acc); }
    else if (ACT == 3) return acc + fmaxf(v * w, 0.f);
    else               { float ex = fast_exp2(v * w); return acc + fast_rcp(1.f + ex); }
}

template<int ACT, bool HS>
__device__ __forceinline__ void seg_run(float& a0, float& a1,
                                        const unsigned short* __restrict__ Xl,  // X + lane*FXS
                                        const float* __restrict__ Hl,           // Hf + lane
                                        unsigned hv, int lo, int hi)
{
    int j = lo;
    #pragma unroll 2
    for (; j + 3 < hi; j += 4) {
        unsigned s0 = (unsigned)rdl((int)hv, j + 2);
        unsigned s1 = (unsigned)rdl((int)hv, j + 3);
        unsigned s2 = (unsigned)rdl((int)hv, j + 4);
        unsigned s3 = (unsigned)rdl((int)hv, j + 5);
        float v0 = HS ? Hl[(s0 & 1023u) * FHS] : bf2f(Xl[s0 & 1023u]);
        float v1 = HS ? Hl[(s1 & 1023u) * FHS] : bf2f(Xl[s1 & 1023u]);
        float v2 = HS ? Hl[(s2 & 1023u) * FHS] : bf2f(Xl[s2 & 1023u]);
        float v3 = HS ? Hl[(s3 & 1023u) * FHS] : bf2f(Xl[s3 & 1023u]);
        a0 = app<ACT>(a0, v0, __uint_as_float(s0 & 0xFFFFFC00u));
        a1 = app<ACT>(a1, v1, __uint_as_float(s1 & 0xFFFFFC00u));
        a0 = app<ACT>(a0, v2, __uint_as_float(s2 & 0xFFFFFC00u));
        a1 = app<ACT>(a1, v3, __uint_as_float(s3 & 0xFFFFFC00u));
    }
    for (; j < hi; ++j) {
        unsigned sp = (unsigned)rdl((int)hv, j + 2);
        float v = HS ? Hl[(sp & 1023u) * FHS] : bf2f(Xl[sp & 1023u]);
        a0 = app<ACT>(a0, v, __uint_as_float(sp & 0xFFFFFC00u));
    }
}

__device__ __forceinline__ int imin(int a, int b) { return a < b ? a : b; }

template<bool OUT>
__device__ __forceinline__ float row_body(unsigned hv, const unsigned* __restrict__ grow,
                                          const unsigned short* __restrict__ Xl,
                                          const float* __restrict__ Hl, int lane)
{
    const unsigned hx = (unsigned)rdl((int)hv, 0);
    const unsigned hy = (unsigned)rdl((int)hv, 1);
    const int c1 = hx & 255, c2 = (hx >> 8) & 255, c3 = (hx >> 16) & 255, c4 = (int)(hx >> 24);
    const int c5 = hy & 255, c6 = (hy >> 8) & 255, c7 = (hy >> 16) & 255, n  = (int)(hy >> 24);
    const int m1 = imin(c1, FASTN), m2 = imin(c2, FASTN), m3 = imin(c3, FASTN), m4 = imin(c4, FASTN);
    const int m5 = imin(c5, FASTN), m6 = imin(c6, FASTN), m7 = imin(c7, FASTN), m8 = imin(n, FASTN);
    // hoisted "+1 per tanh edge" (fast-path portion)
    float a0 = (float)((m2 - m1) + (OUT ? (m6 - m5) : 0));
    float a1 = 0.f;
    seg_run<1,false>(a0, a1, Xl, Hl, hv, 0,  m1);
    seg_run<2,false>(a0, a1, Xl, Hl, hv, m1, m2);
    seg_run<3,false>(a0, a1, Xl, Hl, hv, m2, m3);
    seg_run<4,false>(a0, a1, Xl, Hl, hv, m3, m4);
    if (OUT) {
        seg_run<1,true>(a0, a1, Xl, Hl, hv, m4, m5);
        seg_run<2,true>(a0, a1, Xl, Hl, hv, m5, m6);
        seg_run<3,true>(a0, a1, Xl, Hl, hv, m6, m7);
        seg_run<4,true>(a0, a1, Xl, Hl, hv, m7, m8);
    }
    if (__builtin_expect(n > FASTN, 0)) {
        // rare overflow: edges FASTN.. live at slots 64.. ; uniform per-edge walk
        unsigned hv2 = grow[64 + lane];
        for (int j = FASTN; j < n; ++j) {
            unsigned sp = (unsigned)rdl((int)hv2, j - FASTN);
            int s = (j < c1) ? 0 : (j < c2) ? 1 : (j < c3) ? 2 : (j < c4) ? 3
                  : (j < c5) ? 4 : (j < c6) ? 5 : (j < c7) ? 6 : 7;
            float w = __uint_as_float(sp & 0xFFFFFC00u);
            float v = (s >= 4) ? Hl[(sp & 1023u) * FHS] : bf2f(Xl[sp & 1023u]);
            int a = (s & 3) + 1;
            if (a == 1) a0 = fmaf(v, w, a0);
            else if (a == 2) { float ex = fast_exp2(v * w); a0 += 1.f - 2.f * fast_rcp(1.f + ex); }
            else if (a == 3) a0 += fmaxf(v * w, 0.f);
            else { float ex = fast_exp2(v * w); a0 += fast_rcp(1.f + ex); }
        }
    }
    return a0 + a1;
}

__global__ __launch_bounds__(1024)
void fused_main(const float* __restrict__ x,
                const unsigned* __restrict__ rrh, const unsigned* __restrict__ rro,
                float* __restrict__ out)
{
    extern __shared__ char lds[];
    unsigned short* X   = (unsigned short*)lds;
    float*          Hf  = (float*)(lds + 65792);
    float*          OBT = (float*)lds;                  // overlays X/H after compute
    const int tid  = (int)threadIdx.x;
    const int lane = tid & 63;
    const int wv   = tid >> 6;
    const int rb   = (int)blockIdx.x * 64;
    const unsigned short* Xl = X + (size_t)lane * FXS;
    const float*          Hl = Hf + lane;

    // ---- stage x slab -> bf16 X[64][514], coalesced float4 reads ----
    {
        const float4* xv = (const float4*)(x + (size_t)rb * IN_DIM);
        #pragma unroll
        for (int kk = 0; kk < 8; ++kk) {
            int v = tid + kk * 1024;
            int rr = v >> 7, i = v & 127;
            float4 f = xv[v];
            unsigned int lo = f2bf_rne(f.x) | (f2bf_rne(f.y) << 16);
            unsigned int hi = f2bf_rne(f.z) | (f2bf_rne(f.w) << 16);
            unsigned int* dst = (unsigned int*)&X[rr * FXS + i * 4];
            dst[0] = lo; dst[1] = hi;
        }
    }
    __syncthreads();

    // ---- hidden: wave wv -> rows wv*8..+7, record prefetch pipeline ----
    {
        unsigned hv = rrh[(size_t)(wv * 8) * RSU + lane];
        for (int q = 0; q < 8; ++q) {
            const int r = wv * 8 + q;
            unsigned hvn = hv;
            if (q < 7) hvn = rrh[(size_t)(r + 1) * RSU + lane];
            float acc = row_body<false>(hv, rrh + (size_t)r * RSU, Xl, Hl, lane);
            Hf[r * FHS + lane] = acc;
            hv = hvn;
        }
    }
    __syncthreads();

    // ---- output: wave wv -> rows wv*16..+15, results kept in regs ----
    float res[NO / 16];
    {
        unsigned hv = rro[(size_t)(wv * 16) * RSU + lane];
        #pragma unroll 1
        for (int q = 0; q < 16; ++q) {
            const int r = wv * 16 + q;
            unsigned hvn = hv;
            if (q < 15) hvn = rro[(size_t)(r + 1) * RSU + lane];
            res[q] = fast_tanh(row_body<true>(hv, rro + (size_t)r * RSU, Xl, Hl, lane));
            hv = hvn;
        }
    }
    __syncthreads();

    // ---- OBT transpose (stride 65 -> bank = r + lane, conflict-free) ----
    #pragma unroll
    for (int q = 0; q < NO / 16; ++q)
        OBT[(wv * (NO / 16) + q) * FHS + lane] = res[q];
    __syncthreads();
    // lanes read scattered cols (c = lane + i*64 -> bank = lane + b), stores coalesced 256B/wave
    #pragma unroll
    for (int s = 0; s < 4; ++s) {
        const int b = wv * 4 + s;
        #pragma unroll
        for (int i = 0; i < 4; ++i) {
            const int c = lane + i * 64;
            out[(size_t)(rb + b) * NO + c] = OBT[c * FHS + b];
        }
    }
}

// =============== fallback: single fused kernel, no workspace ===============
#define FT      1024
#define FBPB    64
#define FHS2    65
#define FOBTS   260
#define FLDS    (99072 + 1544)
__device__ __forceinline__ float edge_act2(float z, int a, float k) {
    float ex = fast_exp2(k * z);
    float rc = fast_rcp(1.f + ex);
    return (a == 2) ? (1.f - 2.f * rc) : ((a == 4) ? rc : ((a == 3) ? fmaxf(z, 0.f) : z));
}
__global__ __launch_bounds__(FT)
void wann_fused(const float* __restrict__ x,
                const int* __restrict__ rows_h, const int* __restrict__ cols_h,
                const int* __restrict__ acts_h, const float* __restrict__ wh,
                const int* __restrict__ rows_o, const int* __restrict__ cols_o,
                const int* __restrict__ acts_o, const float* __restrict__ wo,
                float* __restrict__ out, int Eh, int Eo)
{
    extern __shared__ char lds[];
    unsigned short* X   = (unsigned short*)lds;
    float*          H   = (float*)(lds + 65792);
    float*          OBT = (float*)lds;
    int*            offsH = (int*)(lds + 99072);
    int*            offsO = offsH + (NH + 1);
    const int tid  = threadIdx.x;
    const int lane = tid & 63;
    const int wv   = tid >> 6;
    const int rb   = blockIdx.x * FBPB;
    const int* wh_i = (const int*)wh;
    const int* wo_i = (const int*)wo;
    {
        const float4* xv = (const float4*)(x + (size_t)rb * IN_DIM);
        #pragma unroll
        for (int kk = 0; kk < (FBPB * IN_DIM / 4) / FT; ++kk) {
            int v = tid + kk * FT;
            int r = v >> 7, i = v & 127;
            float4 f = xv[v];
            unsigned int lo = (unsigned int)f2bf16s(f.x) | ((unsigned int)f2bf16s(f.y) << 16);
            unsigned int hi = (unsigned int)f2bf16s(f.z) | ((unsigned int)f2bf16s(f.w) << 16);
            unsigned int* dst = (unsigned int*)&X[r * FXS + i * 4];
            dst[0] = lo; dst[1] = hi;
        }
    }
    if (tid <= NH) offsH[tid] = lower_bound_dev(rows_h, Eh, tid);
    else if (tid <= NH + 1 + NO) offsO[tid - (NH + 1)] = lower_bound_dev(rows_o, Eo, tid - (NH + 1));
    __syncthreads();
    for (int r = wv * (NH / 16); r < (wv + 1) * (NH / 16); ++r) {
        const int e0 = rfl(offsH[r]); const int e1 = rfl(offsH[r + 1]);
        float acc = 0.f;
        #pragma unroll 4
        for (int e = e0; e < e1; ++e) {
            int col = rfl(cols_h[e]); int a = rfl(acts_h[e]);
            float w = __int_as_float(rfl(wh_i[e]));
            acc += edge_act2(bf2f(X[lane * FXS + col]) * w, a, act_k(a));
        }
        H[r * FHS2 + lane] = acc;
    }
    __syncthreads();
    float res[NO / 16];
    #pragma unroll
    for (int rr = 0; rr < NO / 16; ++rr) {
        const int r = wv * (NO / 16) + rr;
        const int e0 = rfl(offsO[r]); const int e1 = rfl(offsO[r + 1]);
        float acc = 0.f;
        #pragma unroll 4
        for (int e = e0; e < e1; ++e) {
            int col = rfl(cols_o[e]); int a = rfl(acts_o[e]);
            float w = __int_as_float(rfl(wo_i[e]));
            float v = (col < IN_DIM) ? bf2f(X[lane * FXS + col]) : H[(col - IN_DIM) * FHS2 + lane];
            acc += edge_act2(v * w, a, act_k(a));
        }
        res[rr] = fast_tanh(acc);
    }
    __syncthreads();
    #pragma unroll
    for (int rr = 0; rr < NO / 16; ++rr)
        OBT[lane * FOBTS + wv * (NO / 16) + rr] = res[rr];
    __syncthreads();
    #pragma unroll
    for (int kk = 0; kk < (FBPB * NO / 4) / FT; ++kk) {
        int v = tid + kk * FT;
        int c4 = v & 63, b = v >> 6;
        float4 o = *(const float4*)&OBT[b * FOBTS + c4 * 4];
        *(float4*)&out[(size_t)(rb + b) * NO + c4 * 4] = o;
    }
}

extern "C" void kernel_launch(void* const* d_in, const int* in_sizes, int n_in,
                              void* d_out, int out_size, void* d_ws, size_t ws_size,
                              hipStream_t stream) {
    const float* x      = (const float*)d_in[0];
    const float* wh     = (const float*)d_in[1];
    const float* wo     = (const float*)d_in[2];
    const int*   rows_h = (const int*)d_in[3];
    const int*   cols_h = (const int*)d_in[4];
    const int*   acts_h = (const int*)d_in[5];
    const int*   rows_o = (const int*)d_in[6];
    const int*   cols_o = (const int*)d_in[7];
    const int*   acts_o = (const int*)d_in[8];
    float*       out    = (float*)d_out;

    const int Eh = in_sizes[1];
    const int Eo = in_sizes[2];

    // ws layout: [rrh: NH rows x 512B][rro: NO rows x 512B]
    char*     ws  = (char*)d_ws;
    unsigned* rrh = (unsigned*)ws;
    unsigned* rro = (unsigned*)(ws + (size_t)NH * RSU * 4);
    size_t need = (size_t)(NH + NO) * RSU * 4;

    if (ws_size >= need) {
        prep_rows<<<(NH + NO) * 64 / 512, 512, 0, stream>>>(
            rows_h, cols_h, acts_h, wh, rows_o, cols_o, acts_o, wo,
            Eh, Eo, rrh, rro);
        fused_main<<<BATCH / 64, 1024, MLDS, stream>>>(x, rrh, rro, out);
    } else {
        wann_fused<<<BATCH / FBPB, FT, FLDS, stream>>>(
            x, rows_h, cols_h, acts_h, wh, rows_o, cols_o, acts_o, wo, out, Eh, Eo);
    }
}